// Round 4
// baseline (229.503 us; speedup 1.0000x reference)
//
#include <hip/hip_runtime.h>
#include <math.h>

#define INFBITS 0x7F800000u
#define TCH 64           // target points staged per chamfer block
#define PTS 8            // query points per thread
#define DICE_BLOCKS 512

// ---------- block-wide sum (blockDim.x == 256, 4 waves) ----------
__device__ __forceinline__ float block_sum256(float v) {
#pragma unroll
    for (int o = 32; o > 0; o >>= 1) v += __shfl_down(v, o, 64);
    __shared__ float sb[4];
    if ((threadIdx.x & 63) == 0) sb[threadIdx.x >> 6] = v;
    __syncthreads();
    float r = sb[0] + sb[1] + sb[2] + sb[3];
    __syncthreads();
    return r;
}

// ---------- K1: fused dice partials + chamfer partial mins ----------
// blocks [0, DICE_BLOCKS)            : dice grid-stride partial sums
// blocks [DICE_BLOCKS, +2*gxp*chm)   : chamfer
__global__ void __launch_bounds__(256, 4) fused_partials(
        const float4* __restrict__ p4, const float4* __restrict__ t4, int n4,
        float* __restrict__ inter_p, float* __restrict__ uni_p,
        const float2* __restrict__ P, const float2* __restrict__ T,
        int N, int M, float* __restrict__ pm, int npm, int chm, int gxp,
        unsigned int* __restrict__ counter) {
    int bid = blockIdx.x;
    if (bid == 0 && threadIdx.x == 0) *counter = 0u;   // reset K2's semaphore

    if (bid < DICE_BLOCKS) {
        float inter = 0.f, uni = 0.f;
        for (int i = bid * 256 + threadIdx.x; i < n4; i += DICE_BLOCKS * 256) {
            float4 p = p4[i];
            float4 t = t4[i];
            float s;
            s = __fdividef(1.f, 1.f + __expf(-p.x)); inter = fmaf(s, t.x, inter); uni += s + t.x;
            s = __fdividef(1.f, 1.f + __expf(-p.y)); inter = fmaf(s, t.y, inter); uni += s + t.y;
            s = __fdividef(1.f, 1.f + __expf(-p.z)); inter = fmaf(s, t.z, inter); uni += s + t.z;
            s = __fdividef(1.f, 1.f + __expf(-p.w)); inter = fmaf(s, t.w, inter); uni += s + t.w;
        }
        float bi = block_sum256(inter);
        float bu = block_sum256(uni);
        if (threadIdx.x == 0) { inter_p[bid] = bi; uni_p[bid] = bu; }
        return;
    }

    // ---- chamfer partials ----
    int cb      = bid - DICE_BLOCKS;
    int per_dir = gxp * chm;
    int dir     = cb / per_dir;
    int rem     = cb - dir * per_dir;
    int cy      = rem / gxp;          // target chunk
    int cx      = rem - cy * gxp;     // query-point group
    const float2* A = dir ? T : P;
    const float2* B = dir ? P : T;
    int nA = dir ? M : N;
    int nB = dir ? N : M;

    int tb = cy * TCH;
    if (tb >= nB) return;             // uniform per block

    __shared__ float4 bs[TCH];
    int t = threadIdx.x;
    if (t < TCH) {
        float bx = 0.f, by = 0.f, s2 = __uint_as_float(INFBITS);
        if (tb + t < nB) {
            float2 b = B[tb + t];
            bx = b.x; by = b.y;
            s2 = fmaf(bx, bx, by * by);
        }
        bs[t] = make_float4(bx, by, s2, 0.f);   // OOB pads +inf -> never wins min
    }
    __syncthreads();

    int abase = cx * (PTS * 256);
    float nx[PTS], ny[PTS], sa[PTS], mn[PTS];
#pragma unroll
    for (int i = 0; i < PTS; ++i) {
        int p = abase + i * 256 + t;
        nx[i] = 0.f; ny[i] = 0.f; sa[i] = 0.f;
        mn[i] = __uint_as_float(INFBITS);
        if (p < nA) {
            float2 a = A[p];
            nx[i] = -2.f * a.x;
            ny[i] = -2.f * a.y;
            sa[i] = fmaf(a.x, a.x, a.y * a.y);
        }
    }

    // register double-buffered inner loop: prefetch next 4 targets while
    // computing current 4 -> LDS latency hides under 96 VALU insts
    float4 c0 = bs[0], c1 = bs[1], c2 = bs[2], c3 = bs[3];
#pragma unroll
    for (int jb = 0; jb < TCH / 4; ++jb) {
        int nbi = ((jb + 1) & (TCH / 4 - 1)) * 4;   // wraps to 0 on last iter
        float4 n0 = bs[nbi + 0];
        float4 n1 = bs[nbi + 1];
        float4 n2 = bs[nbi + 2];
        float4 n3 = bs[nbi + 3];
#pragma unroll
        for (int i = 0; i < PTS; ++i)
            mn[i] = fminf(mn[i], fmaf(nx[i], c0.x, fmaf(ny[i], c0.y, c0.z)));
#pragma unroll
        for (int i = 0; i < PTS; ++i)
            mn[i] = fminf(mn[i], fmaf(nx[i], c1.x, fmaf(ny[i], c1.y, c1.z)));
#pragma unroll
        for (int i = 0; i < PTS; ++i)
            mn[i] = fminf(mn[i], fmaf(nx[i], c2.x, fmaf(ny[i], c2.y, c2.z)));
#pragma unroll
        for (int i = 0; i < PTS; ++i)
            mn[i] = fminf(mn[i], fmaf(nx[i], c3.x, fmaf(ny[i], c3.y, c3.z)));
        c0 = n0; c1 = n1; c2 = n2; c3 = n3;
    }

    float* dstc = pm + ((size_t)dir * chm + cy) * npm;
#pragma unroll
    for (int i = 0; i < PTS; ++i) {
        int p = abase + i * 256 + t;
        if (p < nA) dstc[p] = mn[i] + sa[i];
    }
}

// ---------- K2: fused finalize ----------
// grid = 2*gxf blocks; per-point min across chunks + block sum; last block combines.
__global__ void __launch_bounds__(256) finalize_all(
        const float* __restrict__ pm, int npm, int chm,
        int N, int M, int nch0, int nch1,
        const float* __restrict__ inter_p, const float* __restrict__ uni_p,
        float* __restrict__ bsum, unsigned int* __restrict__ counter,
        int gxf, float* __restrict__ out) {
    int blk = blockIdx.x;
    int dir = blk / gxf;
    int bx  = blk - dir * gxf;
    int nA  = dir ? M : N;
    int nch = dir ? nch1 : nch0;

    int p = bx * 256 + threadIdx.x;
    float v = 0.f;
    if (p < nA) {
        const float* src = pm + (size_t)dir * chm * npm + p;
        v = __uint_as_float(INFBITS);
#pragma unroll 8
        for (int c = 0; c < nch; ++c) v = fminf(v, src[(size_t)c * npm]);
    }
    float s = block_sum256(v);

    __shared__ int is_last;
    if (threadIdx.x == 0) {
        bsum[blk] = s;
        __threadfence();
        unsigned int old = atomicAdd(counter, 1u);
        is_last = (old == (unsigned)(2 * gxf - 1));
    }
    __syncthreads();
    if (!is_last) return;
    __threadfence();

    float inter = 0.f, uni = 0.f, c0 = 0.f, c1 = 0.f;
    for (int i = threadIdx.x; i < DICE_BLOCKS; i += 256) {
        inter += inter_p[i];
        uni   += uni_p[i];
    }
    const volatile float* vb = bsum;
    for (int i = threadIdx.x; i < gxf; i += 256) {
        c0 += vb[i];
        c1 += vb[gxf + i];
    }
    float bi  = block_sum256(inter);
    float bu  = block_sum256(uni);
    float bc0 = block_sum256(c0);
    float bc1 = block_sum256(c1);
    if (threadIdx.x == 0) {
        const float SMOOTH = 1e-6f;
        float dice    = (2.f * bi + SMOOTH) / (bu + SMOOTH);
        float chamfer = bc0 / (float)N + bc1 / (float)M;
        out[0] = 0.5f * (1.f - dice) + 0.5f * chamfer;
    }
}

extern "C" void kernel_launch(void* const* d_in, const int* in_sizes, int n_in,
                              void* d_out, int out_size, void* d_ws, size_t ws_size,
                              hipStream_t stream) {
    const float*  pred = (const float*)d_in[0];
    const float*  targ = (const float*)d_in[1];
    const float2* pp   = (const float2*)d_in[2];
    const float2* tp   = (const float2*)d_in[3];
    int n = in_sizes[0];
    int N = in_sizes[2] / 2;
    int M = in_sizes[3] / 2;
    float* out = (float*)d_out;

    int npm  = N > M ? N : M;
    int nch0 = (M + TCH - 1) / TCH;
    int nch1 = (N + TCH - 1) / TCH;
    int chm  = nch0 > nch1 ? nch0 : nch1;
    int gxp  = (npm + PTS * 256 - 1) / (PTS * 256);
    int gxf  = (npm + 255) / 256;

    // ws layout: pm | inter_p | uni_p | bsum | counter
    char*  ws      = (char*)d_ws;
    float* pm      = (float*)ws;
    size_t pm_bytes = (size_t)2 * chm * npm * sizeof(float);
    size_t off     = (pm_bytes + 255) & ~(size_t)255;
    float* inter_p = (float*)(ws + off);
    float* uni_p   = inter_p + DICE_BLOCKS;
    float* bsum    = uni_p + DICE_BLOCKS;
    unsigned int* counter = (unsigned int*)(bsum + 2 * gxf);

    int cham_blocks = 2 * gxp * chm;
    fused_partials<<<DICE_BLOCKS + cham_blocks, 256, 0, stream>>>(
        (const float4*)pred, (const float4*)targ, n / 4,
        inter_p, uni_p, pp, tp, N, M, pm, npm, chm, gxp, counter);

    finalize_all<<<2 * gxf, 256, 0, stream>>>(pm, npm, chm, N, M, nch0, nch1,
                                              inter_p, uni_p, bsum, counter,
                                              gxf, out);
}

// Round 5
// 48.732 us; speedup vs baseline: 4.7095x; 4.7095x over previous
//
#include <hip/hip_runtime.h>
#include <math.h>

#define INFBITS 0x7F800000u
#define TCH 64           // target points staged per chamfer block
#define PTS 8            // query points per thread
#define DICE_BLOCKS 512

// ---------- block-wide sum (blockDim.x == 256, 4 waves) ----------
__device__ __forceinline__ float block_sum256(float v) {
#pragma unroll
    for (int o = 32; o > 0; o >>= 1) v += __shfl_down(v, o, 64);
    __shared__ float sb[4];
    if ((threadIdx.x & 63) == 0) sb[threadIdx.x >> 6] = v;
    __syncthreads();
    float r = sb[0] + sb[1] + sb[2] + sb[3];
    __syncthreads();
    return r;
}

// ---------- K1: fused dice partials + chamfer partial mins ----------
// blocks [0, DICE_BLOCKS)            : dice grid-stride partial sums
// blocks [DICE_BLOCKS, +2*gxp*chm)   : chamfer
// NOTE: no min-wave launch bound — the chamfer inner loop keeps ~100 VGPRs
// live (8x float4 double-buffer + 4x PTS accumulators); capping the
// allocator (R4: __launch_bounds__(256,4)) forced scratch spills -> 187 MB
// of HBM writes per replay and a 6x regression.
__global__ void __launch_bounds__(256) fused_partials(
        const float4* __restrict__ p4, const float4* __restrict__ t4, int n4,
        float* __restrict__ inter_p, float* __restrict__ uni_p,
        const float2* __restrict__ P, const float2* __restrict__ T,
        int N, int M, float* __restrict__ pm, int npm, int chm, int gxp,
        unsigned int* __restrict__ counter) {
    int bid = blockIdx.x;
    if (bid == 0 && threadIdx.x == 0) *counter = 0u;   // reset K2's semaphore

    if (bid < DICE_BLOCKS) {
        float inter = 0.f, uni = 0.f;
        for (int i = bid * 256 + threadIdx.x; i < n4; i += DICE_BLOCKS * 256) {
            float4 p = p4[i];
            float4 t = t4[i];
            float s;
            s = __fdividef(1.f, 1.f + __expf(-p.x)); inter = fmaf(s, t.x, inter); uni += s + t.x;
            s = __fdividef(1.f, 1.f + __expf(-p.y)); inter = fmaf(s, t.y, inter); uni += s + t.y;
            s = __fdividef(1.f, 1.f + __expf(-p.z)); inter = fmaf(s, t.z, inter); uni += s + t.z;
            s = __fdividef(1.f, 1.f + __expf(-p.w)); inter = fmaf(s, t.w, inter); uni += s + t.w;
        }
        float bi = block_sum256(inter);
        float bu = block_sum256(uni);
        if (threadIdx.x == 0) { inter_p[bid] = bi; uni_p[bid] = bu; }
        return;
    }

    // ---- chamfer partials ----
    int cb      = bid - DICE_BLOCKS;
    int per_dir = gxp * chm;
    int dir     = cb / per_dir;
    int rem     = cb - dir * per_dir;
    int cy      = rem / gxp;          // target chunk
    int cx      = rem - cy * gxp;     // query-point group
    const float2* A = dir ? T : P;
    const float2* B = dir ? P : T;
    int nA = dir ? M : N;
    int nB = dir ? N : M;

    int tb = cy * TCH;
    if (tb >= nB) return;             // uniform per block

    __shared__ float4 bs[TCH];
    int t = threadIdx.x;
    if (t < TCH) {
        float bx = 0.f, by = 0.f, s2 = __uint_as_float(INFBITS);
        if (tb + t < nB) {
            float2 b = B[tb + t];
            bx = b.x; by = b.y;
            s2 = fmaf(bx, bx, by * by);
        }
        bs[t] = make_float4(bx, by, s2, 0.f);   // OOB pads +inf -> never wins min
    }
    __syncthreads();

    int abase = cx * (PTS * 256);
    float nx[PTS], ny[PTS], sa[PTS], mn[PTS];
#pragma unroll
    for (int i = 0; i < PTS; ++i) {
        int p = abase + i * 256 + t;
        nx[i] = 0.f; ny[i] = 0.f; sa[i] = 0.f;
        mn[i] = __uint_as_float(INFBITS);
        if (p < nA) {
            float2 a = A[p];
            nx[i] = -2.f * a.x;
            ny[i] = -2.f * a.y;
            sa[i] = fmaf(a.x, a.x, a.y * a.y);
        }
    }

    // register double-buffered inner loop: prefetch next 4 targets while
    // computing current 4 -> LDS latency hides under 96 VALU insts
    float4 c0 = bs[0], c1 = bs[1], c2 = bs[2], c3 = bs[3];
#pragma unroll
    for (int jb = 0; jb < TCH / 4; ++jb) {
        int nbi = ((jb + 1) & (TCH / 4 - 1)) * 4;   // wraps to 0 on last iter
        float4 n0 = bs[nbi + 0];
        float4 n1 = bs[nbi + 1];
        float4 n2 = bs[nbi + 2];
        float4 n3 = bs[nbi + 3];
#pragma unroll
        for (int i = 0; i < PTS; ++i)
            mn[i] = fminf(mn[i], fmaf(nx[i], c0.x, fmaf(ny[i], c0.y, c0.z)));
#pragma unroll
        for (int i = 0; i < PTS; ++i)
            mn[i] = fminf(mn[i], fmaf(nx[i], c1.x, fmaf(ny[i], c1.y, c1.z)));
#pragma unroll
        for (int i = 0; i < PTS; ++i)
            mn[i] = fminf(mn[i], fmaf(nx[i], c2.x, fmaf(ny[i], c2.y, c2.z)));
#pragma unroll
        for (int i = 0; i < PTS; ++i)
            mn[i] = fminf(mn[i], fmaf(nx[i], c3.x, fmaf(ny[i], c3.y, c3.z)));
        c0 = n0; c1 = n1; c2 = n2; c3 = n3;
    }

    float* dstc = pm + ((size_t)dir * chm + cy) * npm;
#pragma unroll
    for (int i = 0; i < PTS; ++i) {
        int p = abase + i * 256 + t;
        if (p < nA) dstc[p] = mn[i] + sa[i];
    }
}

// ---------- K2: fused finalize ----------
// grid = 2*gxf blocks; per-point min across chunks + block sum; last block combines.
__global__ void __launch_bounds__(256) finalize_all(
        const float* __restrict__ pm, int npm, int chm,
        int N, int M, int nch0, int nch1,
        const float* __restrict__ inter_p, const float* __restrict__ uni_p,
        float* __restrict__ bsum, unsigned int* __restrict__ counter,
        int gxf, float* __restrict__ out) {
    int blk = blockIdx.x;
    int dir = blk / gxf;
    int bx  = blk - dir * gxf;
    int nA  = dir ? M : N;
    int nch = dir ? nch1 : nch0;

    int p = bx * 256 + threadIdx.x;
    float v = 0.f;
    if (p < nA) {
        const float* src = pm + (size_t)dir * chm * npm + p;
        v = __uint_as_float(INFBITS);
#pragma unroll 8
        for (int c = 0; c < nch; ++c) v = fminf(v, src[(size_t)c * npm]);
    }
    float s = block_sum256(v);

    __shared__ int is_last;
    if (threadIdx.x == 0) {
        bsum[blk] = s;
        __threadfence();
        unsigned int old = atomicAdd(counter, 1u);
        is_last = (old == (unsigned)(2 * gxf - 1));
    }
    __syncthreads();
    if (!is_last) return;
    __threadfence();

    float inter = 0.f, uni = 0.f, c0 = 0.f, c1 = 0.f;
    for (int i = threadIdx.x; i < DICE_BLOCKS; i += 256) {
        inter += inter_p[i];
        uni   += uni_p[i];
    }
    const volatile float* vb = bsum;
    for (int i = threadIdx.x; i < gxf; i += 256) {
        c0 += vb[i];
        c1 += vb[gxf + i];
    }
    float bi  = block_sum256(inter);
    float bu  = block_sum256(uni);
    float bc0 = block_sum256(c0);
    float bc1 = block_sum256(c1);
    if (threadIdx.x == 0) {
        const float SMOOTH = 1e-6f;
        float dice    = (2.f * bi + SMOOTH) / (bu + SMOOTH);
        float chamfer = bc0 / (float)N + bc1 / (float)M;
        out[0] = 0.5f * (1.f - dice) + 0.5f * chamfer;
    }
}

extern "C" void kernel_launch(void* const* d_in, const int* in_sizes, int n_in,
                              void* d_out, int out_size, void* d_ws, size_t ws_size,
                              hipStream_t stream) {
    const float*  pred = (const float*)d_in[0];
    const float*  targ = (const float*)d_in[1];
    const float2* pp   = (const float2*)d_in[2];
    const float2* tp   = (const float2*)d_in[3];
    int n = in_sizes[0];
    int N = in_sizes[2] / 2;
    int M = in_sizes[3] / 2;
    float* out = (float*)d_out;

    int npm  = N > M ? N : M;
    int nch0 = (M + TCH - 1) / TCH;
    int nch1 = (N + TCH - 1) / TCH;
    int chm  = nch0 > nch1 ? nch0 : nch1;
    int gxp  = (npm + PTS * 256 - 1) / (PTS * 256);
    int gxf  = (npm + 255) / 256;

    // ws layout: pm | inter_p | uni_p | bsum | counter
    char*  ws      = (char*)d_ws;
    float* pm      = (float*)ws;
    size_t pm_bytes = (size_t)2 * chm * npm * sizeof(float);
    size_t off     = (pm_bytes + 255) & ~(size_t)255;
    float* inter_p = (float*)(ws + off);
    float* uni_p   = inter_p + DICE_BLOCKS;
    float* bsum    = uni_p + DICE_BLOCKS;
    unsigned int* counter = (unsigned int*)(bsum + 2 * gxf);

    int cham_blocks = 2 * gxp * chm;
    fused_partials<<<DICE_BLOCKS + cham_blocks, 256, 0, stream>>>(
        (const float4*)pred, (const float4*)targ, n / 4,
        inter_p, uni_p, pp, tp, N, M, pm, npm, chm, gxp, counter);

    finalize_all<<<2 * gxf, 256, 0, stream>>>(pm, npm, chm, N, M, nch0, nch1,
                                              inter_p, uni_p, bsum, counter,
                                              gxf, out);
}

// Round 6
// 28.640 us; speedup vs baseline: 8.0134x; 1.7015x over previous
//
#include <hip/hip_runtime.h>
#include <math.h>

#define INFBITS 0x7F800000u
#define TCH 128          // target points staged per chamfer block
#define PTS 8            // query points per thread
#define DICE_BLOCKS 512

// ---------- block-wide sum (blockDim.x == 256, 4 waves) ----------
__device__ __forceinline__ float block_sum256(float v) {
#pragma unroll
    for (int o = 32; o > 0; o >>= 1) v += __shfl_down(v, o, 64);
    __shared__ float sb[4];
    if ((threadIdx.x & 63) == 0) sb[threadIdx.x >> 6] = v;
    __syncthreads();
    float r = sb[0] + sb[1] + sb[2] + sb[3];
    __syncthreads();
    return r;
}

// ---------- K1: fused dice partials + chamfer partial mins ----------
// blocks [0, DICE_BLOCKS)          : dice grid-stride partial sums
// blocks [DICE_BLOCKS, +2*gxp*chm) : chamfer partial mins
//
// Register budget is the whole game (R4/R5 lesson): VGPR must stay <= 64 for
// 8 waves/SIMD. So: no manual double-buffer (TLP hides LDS latency), and the
// per-point ||a||^2 term is NOT kept or added here — min_j(||b||^2 - 2 a.b)
// is invariant to the additive per-point constant, so K2 adds ||a||^2 after
// the cross-chunk min. Chamfer state = nx/ny/mn = 24 VGPRs.
__global__ void __launch_bounds__(256) fused_partials(
        const float4* __restrict__ p4, const float4* __restrict__ t4, int n4,
        float* __restrict__ inter_p, float* __restrict__ uni_p,
        const float2* __restrict__ P, const float2* __restrict__ T,
        int N, int M, float* __restrict__ pm, int npm, int chm, int gxp,
        unsigned int* __restrict__ counter) {
    int bid = blockIdx.x;
    if (bid == 0 && threadIdx.x == 0) *counter = 0u;   // reset K2's semaphore

    if (bid < DICE_BLOCKS) {
        float inter = 0.f, uni = 0.f;
#pragma unroll 2
        for (int i = bid * 256 + threadIdx.x; i < n4; i += DICE_BLOCKS * 256) {
            float4 p = p4[i];
            float4 t = t4[i];
            float s;
            s = __fdividef(1.f, 1.f + __expf(-p.x)); inter = fmaf(s, t.x, inter); uni += s + t.x;
            s = __fdividef(1.f, 1.f + __expf(-p.y)); inter = fmaf(s, t.y, inter); uni += s + t.y;
            s = __fdividef(1.f, 1.f + __expf(-p.z)); inter = fmaf(s, t.z, inter); uni += s + t.z;
            s = __fdividef(1.f, 1.f + __expf(-p.w)); inter = fmaf(s, t.w, inter); uni += s + t.w;
        }
        float bi = block_sum256(inter);
        float bu = block_sum256(uni);
        if (threadIdx.x == 0) { inter_p[bid] = bi; uni_p[bid] = bu; }
        return;
    }

    // ---- chamfer partials ----
    int cb      = bid - DICE_BLOCKS;
    int per_dir = gxp * chm;
    int dir     = cb / per_dir;
    int rem     = cb - dir * per_dir;
    int cy      = rem / gxp;          // target chunk
    int cx      = rem - cy * gxp;     // query-point group
    const float2* A = dir ? T : P;
    const float2* B = dir ? P : T;
    int nA = dir ? M : N;
    int nB = dir ? N : M;

    int tb = cy * TCH;
    if (tb >= nB) return;             // uniform per block

    __shared__ float4 bs[TCH];
    int t = threadIdx.x;
    if (t < TCH) {
        float bx = 0.f, by = 0.f, s2 = __uint_as_float(INFBITS);
        if (tb + t < nB) {
            float2 b = B[tb + t];
            bx = b.x; by = b.y;
            s2 = fmaf(bx, bx, by * by);
        }
        bs[t] = make_float4(bx, by, s2, 0.f);   // OOB pads +inf -> never wins min
    }
    __syncthreads();

    int abase = cx * (PTS * 256);
    float nx[PTS], ny[PTS], mn[PTS];
#pragma unroll
    for (int i = 0; i < PTS; ++i) {
        int p = abase + i * 256 + t;
        nx[i] = 0.f; ny[i] = 0.f;
        mn[i] = __uint_as_float(INFBITS);
        if (p < nA) {
            float2 a = A[p];
            nx[i] = -2.f * a.x;
            ny[i] = -2.f * a.y;
        }
    }

    // bs[j] is wave-uniform -> broadcast LDS read; TLP (8 waves/SIMD) hides
    // latency; unroll 4 gives the scheduler 4 loads to hoist per 96 VALU.
#pragma unroll 4
    for (int j = 0; j < TCH; ++j) {
        float4 b = bs[j];
#pragma unroll
        for (int i = 0; i < PTS; ++i)
            mn[i] = fminf(mn[i], fmaf(nx[i], b.x, fmaf(ny[i], b.y, b.z)));
    }

    float* dstc = pm + ((size_t)dir * chm + cy) * npm;
#pragma unroll
    for (int i = 0; i < PTS; ++i) {
        int p = abase + i * 256 + t;
        if (p < nA) dstc[p] = mn[i];
    }
}

// ---------- K2: fused finalize ----------
// grid = 2*gxf blocks; per-point min across chunks, + ||a||^2, block sum;
// last block combines dice partials + chamfer block sums into the scalar.
__global__ void __launch_bounds__(256) finalize_all(
        const float* __restrict__ pm, int npm, int chm,
        int N, int M, int nch0, int nch1,
        const float2* __restrict__ P, const float2* __restrict__ T,
        const float* __restrict__ inter_p, const float* __restrict__ uni_p,
        float* __restrict__ bsum, unsigned int* __restrict__ counter,
        int gxf, float* __restrict__ out) {
    int blk = blockIdx.x;
    int dir = blk / gxf;
    int bx  = blk - dir * gxf;
    int nA  = dir ? M : N;
    int nch = dir ? nch1 : nch0;
    const float2* A = dir ? T : P;

    int p = bx * 256 + threadIdx.x;
    float v = 0.f;
    if (p < nA) {
        const float* src = pm + (size_t)dir * chm * npm + p;
        float m = __uint_as_float(INFBITS);
#pragma unroll 8
        for (int c = 0; c < nch; ++c) m = fminf(m, src[(size_t)c * npm]);
        float2 a = A[p];
        v = m + fmaf(a.x, a.x, a.y * a.y);   // add the deferred ||a||^2
    }
    float s = block_sum256(v);

    __shared__ int is_last;
    if (threadIdx.x == 0) {
        bsum[blk] = s;
        __threadfence();
        unsigned int old = atomicAdd(counter, 1u);
        is_last = (old == (unsigned)(2 * gxf - 1));
    }
    __syncthreads();
    if (!is_last) return;
    __threadfence();

    float inter = 0.f, uni = 0.f, c0 = 0.f, c1 = 0.f;
    for (int i = threadIdx.x; i < DICE_BLOCKS; i += 256) {
        inter += inter_p[i];
        uni   += uni_p[i];
    }
    const volatile float* vb = bsum;
    for (int i = threadIdx.x; i < gxf; i += 256) {
        c0 += vb[i];
        c1 += vb[gxf + i];
    }
    float bi  = block_sum256(inter);
    float bu  = block_sum256(uni);
    float bc0 = block_sum256(c0);
    float bc1 = block_sum256(c1);
    if (threadIdx.x == 0) {
        const float SMOOTH = 1e-6f;
        float dice    = (2.f * bi + SMOOTH) / (bu + SMOOTH);
        float chamfer = bc0 / (float)N + bc1 / (float)M;
        out[0] = 0.5f * (1.f - dice) + 0.5f * chamfer;
    }
}

extern "C" void kernel_launch(void* const* d_in, const int* in_sizes, int n_in,
                              void* d_out, int out_size, void* d_ws, size_t ws_size,
                              hipStream_t stream) {
    const float*  pred = (const float*)d_in[0];
    const float*  targ = (const float*)d_in[1];
    const float2* pp   = (const float2*)d_in[2];
    const float2* tp   = (const float2*)d_in[3];
    int n = in_sizes[0];
    int N = in_sizes[2] / 2;
    int M = in_sizes[3] / 2;
    float* out = (float*)d_out;

    int npm  = N > M ? N : M;
    int nch0 = (M + TCH - 1) / TCH;
    int nch1 = (N + TCH - 1) / TCH;
    int chm  = nch0 > nch1 ? nch0 : nch1;
    int gxp  = (npm + PTS * 256 - 1) / (PTS * 256);
    int gxf  = (npm + 255) / 256;

    // ws layout: pm | inter_p | uni_p | bsum | counter
    char*  ws      = (char*)d_ws;
    float* pm      = (float*)ws;
    size_t pm_bytes = (size_t)2 * chm * npm * sizeof(float);
    size_t off     = (pm_bytes + 255) & ~(size_t)255;
    float* inter_p = (float*)(ws + off);
    float* uni_p   = inter_p + DICE_BLOCKS;
    float* bsum    = uni_p + DICE_BLOCKS;
    unsigned int* counter = (unsigned int*)(bsum + 2 * gxf);

    int cham_blocks = 2 * gxp * chm;
    fused_partials<<<DICE_BLOCKS + cham_blocks, 256, 0, stream>>>(
        (const float4*)pred, (const float4*)targ, n / 4,
        inter_p, uni_p, pp, tp, N, M, pm, npm, chm, gxp, counter);

    finalize_all<<<2 * gxf, 256, 0, stream>>>(pm, npm, chm, N, M, nch0, nch1,
                                              pp, tp, inter_p, uni_p, bsum,
                                              counter, gxf, out);
}